// Round 1
// baseline (314.303 us; speedup 1.0000x reference)
//
#include <hip/hip_runtime.h>

using short8  = __attribute__((ext_vector_type(8))) short;
using ushort8v = __attribute__((ext_vector_type(8))) unsigned short;
using f32x4   = __attribute__((ext_vector_type(4))) float;

__device__ __forceinline__ unsigned short f2bf(float x){
  union { float f; unsigned u; } c; c.f = x;
  unsigned u = c.u + 0x7FFFu + ((c.u >> 16) & 1u);
  return (unsigned short)(u >> 16);
}

// ---------------- conversions ----------------
__global__ void cvt4(const float* __restrict__ src, unsigned short* __restrict__ dst,
                     int n, float scale){
  int i = (blockIdx.x * blockDim.x + threadIdx.x) * 4;
  if (i >= n) return;
  float4 v = *(const float4*)(src + i);
  ushort4 o;
  o.x = f2bf(v.x * scale); o.y = f2bf(v.y * scale);
  o.z = f2bf(v.z * scale); o.w = f2bf(v.w * scale);
  *(ushort4*)(dst + i) = o;
}

__global__ void cvt_mask(const int* __restrict__ src, unsigned char* __restrict__ dst, int n){
  int i = (blockIdx.x * blockDim.x + threadIdx.x) * 4;
  if (i >= n) return;
  int4 v = *(const int4*)(src + i);
  unsigned out = (v.x ? 1u : 0u) | ((v.y ? 1u : 0u) << 8) |
                 ((v.z ? 1u : 0u) << 16) | ((v.w ? 1u : 0u) << 24);
  *(unsigned*)(dst + i) = out;
}

// ---------------- async global->LDS, width 16 ----------------
__device__ __forceinline__ void stage16(const unsigned short* g, unsigned short* l){
  __builtin_amdgcn_global_load_lds(
      (const __attribute__((address_space(1))) void*)g,
      (__attribute__((address_space(3))) void*)l, 16, 0, 0);
}

// ---------------- GEMM: C[M,N] = A[M,K] * B[N,K]^T  (bf16 in, bf16 or f32 out) ----
// m97 recipe: 128x128 tile, BK=32, 4 waves each 64x64 via 4x4 16x16x32 MFMA.
template<bool F32OUT>
__global__ __launch_bounds__(256) void gemm_bt(const unsigned short* __restrict__ A,
                                               const unsigned short* __restrict__ B,
                                               unsigned short* __restrict__ Cb,
                                               float* __restrict__ Cf,
                                               int M, int N, int K)
{
  __shared__ unsigned short As[128*32];
  __shared__ unsigned short Bs[128*32];
  const int tid = threadIdx.x;
  const int wave = tid >> 6, lane = tid & 63, l16 = lane & 15, quad = lane >> 4;
  const int bm = blockIdx.x * 128, bn = blockIdx.y * 128;
  const int wm = (wave >> 1) * 64, wn = (wave & 1) * 64;

  f32x4 acc[4][4] = {};

  for (int k0 = 0; k0 < K; k0 += 32){
    #pragma unroll
    for (int c = 0; c < 2; c++){
      int idx = c * 256 + tid;
      int row = idx >> 2, g = (idx & 3) * 8;   // 128 rows x 4 groups of 8 bf16 (16B)
      stage16(A + (size_t)(bm + row) * K + k0 + g, &As[idx * 8]);
      stage16(B + (size_t)(bn + row) * K + k0 + g, &Bs[idx * 8]);
    }
    __syncthreads();
    short8 af[4], bf[4];
    #pragma unroll
    for (int i = 0; i < 4; i++) af[i] = *(const short8*)&As[(wm + i*16 + l16)*32 + quad*8];
    #pragma unroll
    for (int j = 0; j < 4; j++) bf[j] = *(const short8*)&Bs[(wn + j*16 + l16)*32 + quad*8];
    #pragma unroll
    for (int i = 0; i < 4; i++)
      #pragma unroll
      for (int j = 0; j < 4; j++)
        acc[i][j] = __builtin_amdgcn_mfma_f32_16x16x32_bf16(af[i], bf[j], acc[i][j], 0, 0, 0);
    __syncthreads();
  }

  #pragma unroll
  for (int i = 0; i < 4; i++){
    int mrow = bm + wm + i*16 + quad*4;
    #pragma unroll
    for (int j = 0; j < 4; j++){
      int ncol = bn + wn + j*16 + l16;
      #pragma unroll
      for (int r = 0; r < 4; r++){
        if (F32OUT) Cf[(size_t)(mrow + r) * N + ncol] = acc[i][j][r];
        else        Cb[(size_t)(mrow + r) * N + ncol] = f2bf(acc[i][j][r]);
      }
    }
  }
}

// ---------------- flash attention (no-max online softmax) ----------------
// QKV: [4096][3072] bf16 rows b*2048+s; Q at col h*64, K at 1024+h*64, V at 2048+h*64.
// Q pre-scaled by 1/8 (folded into Wq). Masked scores replaced by -1e-9 (sic, per ref).
__global__ __launch_bounds__(256) void attn(const unsigned short* __restrict__ QKV,
                                            const unsigned char* __restrict__ mask8,
                                            unsigned short* __restrict__ O)
{
  constexpr int LDK = 72;                 // 144B row stride: 16B-aligned, conflict-light
  __shared__ unsigned short Ks[64 * LDK];
  __shared__ unsigned short Vt[64 * LDK]; // transposed: Vt[hd][key]
  __shared__ unsigned short Ps[64 * LDK]; // P round-trip, 16 rows per wave
  const int tid = threadIdx.x, wave = tid >> 6, lane = tid & 63;
  const int l16 = lane & 15, quad = lane >> 4;
  const int b = blockIdx.y >> 4, h = blockIdx.y & 15;
  const int qw = blockIdx.x * 64 + wave * 16;        // this wave's q base
  const unsigned short* Qbase = QKV + (size_t)b * 2048 * 3072 + h * 64;
  const unsigned short* Kbase = Qbase + 1024;
  const unsigned short* Vbase = Qbase + 2048;
  const unsigned char* mrow = mask8 + (size_t)b * 2048 * 2048;

  short8 qf[2];
  #pragma unroll
  for (int ks = 0; ks < 2; ks++)
    qf[ks] = *(const short8*)(Qbase + (size_t)(qw + l16) * 3072 + ks*32 + quad*8);

  f32x4 oacc[4] = {};
  float lsum[4] = {0.f, 0.f, 0.f, 0.f};
  const int vkp = tid >> 3, vg = tid & 7;

  for (int j0 = 0; j0 < 2048; j0 += 64){
    __syncthreads();                       // protect LDS from prev-iter readers
    // stage K chunk: 64 rows x 64 cols bf16, natural layout
    #pragma unroll
    for (int c = 0; c < 2; c++){
      int idx = c * 256 + tid;
      int row = idx >> 3, g = (idx & 7) * 8;
      *(short8*)&Ks[row * LDK + g] = *(const short8*)(Kbase + (size_t)(j0 + row) * 3072 + g);
    }
    // stage V transposed: Vt[hd][key], paired-key 4B writes
    {
      ushort8v v0 = *(const ushort8v*)(Vbase + (size_t)(j0 + 2*vkp    ) * 3072 + vg*8);
      ushort8v v1 = *(const ushort8v*)(Vbase + (size_t)(j0 + 2*vkp + 1) * 3072 + vg*8);
      #pragma unroll
      for (int j = 0; j < 8; j++){
        unsigned pair = (unsigned)v0[j] | ((unsigned)v1[j] << 16);
        *(unsigned*)&Vt[(vg*8 + j) * LDK + 2*vkp] = pair;
      }
    }
    __syncthreads();

    // S = Q * K^T  (D row = q = quad*4+reg, col = key = n*16+l16)
    f32x4 sacc[4];
    #pragma unroll
    for (int n = 0; n < 4; n++){
      f32x4 a = {0.f, 0.f, 0.f, 0.f};
      #pragma unroll
      for (int ks = 0; ks < 2; ks++){
        short8 kf = *(const short8*)&Ks[(n*16 + l16) * LDK + ks*32 + quad*8];
        a = __builtin_amdgcn_mfma_f32_16x16x32_bf16(qf[ks], kf, a, 0, 0, 0);
      }
      sacc[n] = a;
    }

    // mask, exp (no max: scores O(1), masked -> exp(-1e-9)=1), accumulate row sums,
    // spill P to LDS in A-layout-readable form
    #pragma unroll
    for (int n = 0; n < 4; n++){
      int kcol = j0 + n*16 + l16;
      #pragma unroll
      for (int r = 0; r < 4; r++){
        int qrow = qw + quad*4 + r;
        float s = mrow[(size_t)qrow * 2048 + kcol] ? sacc[n][r] : -1e-9f;
        float p = __expf(s);
        lsum[r] += p;
        Ps[(wave*16 + quad*4 + r) * LDK + n*16 + l16] = f2bf(p);
      }
    }
    __asm__ volatile("s_waitcnt lgkmcnt(0)" ::: "memory"); // wave-local LDS visibility

    // O += P * V   (A = P: m=l16, k=quad*8+j; B = V via Vt[hd][key])
    short8 pf0 = *(const short8*)&Ps[(wave*16 + l16) * LDK      + quad*8];
    short8 pf1 = *(const short8*)&Ps[(wave*16 + l16) * LDK + 32 + quad*8];
    #pragma unroll
    for (int n = 0; n < 4; n++){
      short8 vf0 = *(const short8*)&Vt[(n*16 + l16) * LDK      + quad*8];
      short8 vf1 = *(const short8*)&Vt[(n*16 + l16) * LDK + 32 + quad*8];
      oacc[n] = __builtin_amdgcn_mfma_f32_16x16x32_bf16(pf0, vf0, oacc[n], 0, 0, 0);
      oacc[n] = __builtin_amdgcn_mfma_f32_16x16x32_bf16(pf1, vf1, oacc[n], 0, 0, 0);
    }
  }

  // normalize: reduce lsum across the 16 lanes of each quad-row group
  float linv[4];
  #pragma unroll
  for (int r = 0; r < 4; r++){
    float v = lsum[r];
    v += __shfl_xor(v, 1); v += __shfl_xor(v, 2);
    v += __shfl_xor(v, 4); v += __shfl_xor(v, 8);
    linv[r] = 1.0f / v;
  }
  #pragma unroll
  for (int n = 0; n < 4; n++)
    #pragma unroll
    for (int r = 0; r < 4; r++){
      int qrow = qw + quad*4 + r;
      O[(size_t)(b*2048 + qrow) * 1024 + h*64 + n*16 + l16] = f2bf(oacc[n][r] * linv[r]);
    }
}

// ---------------- launch ----------------
extern "C" void kernel_launch(void* const* d_in, const int* in_sizes, int n_in,
                              void* d_out, int out_size, void* d_ws, size_t ws_size,
                              hipStream_t stream)
{
  const float* X  = (const float*)d_in[0];
  const int*   Mk = (const int*)d_in[1];
  const float* Wq = (const float*)d_in[2];
  const float* Wk = (const float*)d_in[3];
  const float* Wv = (const float*)d_in[4];
  const float* Wo = (const float*)d_in[5];
  float* out = (float*)d_out;

  char* ws = (char*)d_ws;
  unsigned short* Xb   = (unsigned short*)(ws + 0);          //  8 MB  [4096][1024]
  unsigned short* Wqkv = (unsigned short*)(ws + 8388608);    //  6 MB  [3072][1024]
  unsigned short* Wob  = (unsigned short*)(ws + 14680064);   //  2 MB  [1024][1024]
  unsigned short* QKV  = (unsigned short*)(ws + 16777216);   // 24 MB  [4096][3072]
  unsigned short* Ob   = (unsigned short*)(ws + 41943040);   //  8 MB  [4096][1024]
  unsigned char*  M8   = (unsigned char*) (ws + 50331648);   //  8 MB  [2][2048][2048]

  cvt4<<<4096, 256, 0, stream>>>(X,  Xb,              4194304, 1.0f);
  cvt4<<<1024, 256, 0, stream>>>(Wq, Wqkv,            1048576, 0.125f); // fold 1/sqrt(64)
  cvt4<<<1024, 256, 0, stream>>>(Wk, Wqkv + 1048576,  1048576, 1.0f);
  cvt4<<<1024, 256, 0, stream>>>(Wv, Wqkv + 2097152,  1048576, 1.0f);
  cvt4<<<1024, 256, 0, stream>>>(Wo, Wob,             1048576, 1.0f);
  cvt_mask<<<8192, 256, 0, stream>>>(Mk, M8, 8388608);

  gemm_bt<false><<<dim3(32, 24), 256, 0, stream>>>(Xb, Wqkv, QKV, nullptr, 4096, 3072, 1024);
  attn<<<dim3(32, 32), 256, 0, stream>>>(QKV, M8, Ob);
  gemm_bt<true><<<dim3(32, 8), 256, 0, stream>>>(Ob, Wob, nullptr, out, 4096, 1024, 1024);
}

// Round 2
// 294.989 us; speedup vs baseline: 1.0655x; 1.0655x over previous
//
#include <hip/hip_runtime.h>
#include <hip/hip_bf16.h>

using short8  = __attribute__((ext_vector_type(8))) short;
using short4v = __attribute__((ext_vector_type(4))) short;
using f32x4   = __attribute__((ext_vector_type(4))) float;

__device__ __forceinline__ unsigned short f2bf(float x){
  union { float f; unsigned u; } c; c.f = x;
  unsigned u = c.u + 0x7FFFu + ((c.u >> 16) & 1u);
  return (unsigned short)(u >> 16);
}

__device__ __forceinline__ unsigned pack_bf16_rn(float a, float b){
  __hip_bfloat162 t = __float22bfloat162_rn(make_float2(a, b));
  unsigned u; __builtin_memcpy(&u, &t, 4);
  return u;
}

// ---------------- conversions ----------------
__global__ void cvt4(const float* __restrict__ src, unsigned short* __restrict__ dst,
                     int n, float scale){
  int i = (blockIdx.x * blockDim.x + threadIdx.x) * 4;
  if (i >= n) return;
  float4 v = *(const float4*)(src + i);
  ushort4 o;
  o.x = f2bf(v.x * scale); o.y = f2bf(v.y * scale);
  o.z = f2bf(v.z * scale); o.w = f2bf(v.w * scale);
  *(ushort4*)(dst + i) = o;
}

__global__ void cvt_mask(const int* __restrict__ src, unsigned char* __restrict__ dst, int n){
  int i = (blockIdx.x * blockDim.x + threadIdx.x) * 4;
  if (i >= n) return;
  int4 v = *(const int4*)(src + i);
  unsigned out = (v.x ? 1u : 0u) | ((v.y ? 1u : 0u) << 8) |
                 ((v.z ? 1u : 0u) << 16) | ((v.w ? 1u : 0u) << 24);
  *(unsigned*)(dst + i) = out;
}

// ---------------- async global->LDS, width 16 ----------------
__device__ __forceinline__ void stage16(const unsigned short* g, unsigned short* l){
  __builtin_amdgcn_global_load_lds(
      (const __attribute__((address_space(1))) void*)g,
      (__attribute__((address_space(3))) void*)l, 16, 0, 0);
}

// ---------------- GEMM: C[M,N] = A[M,K] * B[N,K]^T ----------------
template<bool F32OUT>
__global__ __launch_bounds__(256) void gemm_bt(const unsigned short* __restrict__ A,
                                               const unsigned short* __restrict__ B,
                                               unsigned short* __restrict__ Cb,
                                               float* __restrict__ Cf,
                                               int M, int N, int K)
{
  __shared__ unsigned short As[128*32];
  __shared__ unsigned short Bs[128*32];
  const int tid = threadIdx.x;
  const int wave = tid >> 6, lane = tid & 63, l16 = lane & 15, quad = lane >> 4;
  const int bm = blockIdx.x * 128, bn = blockIdx.y * 128;
  const int wm = (wave >> 1) * 64, wn = (wave & 1) * 64;

  f32x4 acc[4][4] = {};

  for (int k0 = 0; k0 < K; k0 += 32){
    #pragma unroll
    for (int c = 0; c < 2; c++){
      int idx = c * 256 + tid;
      int row = idx >> 2, g = (idx & 3) * 8;
      stage16(A + (size_t)(bm + row) * K + k0 + g, &As[idx * 8]);
      stage16(B + (size_t)(bn + row) * K + k0 + g, &Bs[idx * 8]);
    }
    __syncthreads();
    short8 af[4], bf[4];
    #pragma unroll
    for (int i = 0; i < 4; i++) af[i] = *(const short8*)&As[(wm + i*16 + l16)*32 + quad*8];
    #pragma unroll
    for (int j = 0; j < 4; j++) bf[j] = *(const short8*)&Bs[(wn + j*16 + l16)*32 + quad*8];
    #pragma unroll
    for (int i = 0; i < 4; i++)
      #pragma unroll
      for (int j = 0; j < 4; j++)
        acc[i][j] = __builtin_amdgcn_mfma_f32_16x16x32_bf16(af[i], bf[j], acc[i][j], 0, 0, 0);
    __syncthreads();
  }

  #pragma unroll
  for (int i = 0; i < 4; i++){
    int mrow = bm + wm + i*16 + quad*4;
    #pragma unroll
    for (int j = 0; j < 4; j++){
      int ncol = bn + wn + j*16 + l16;
      #pragma unroll
      for (int r = 0; r < 4; r++){
        if (F32OUT) Cf[(size_t)(mrow + r) * N + ncol] = acc[i][j][r];
        else        Cb[(size_t)(mrow + r) * N + ncol] = f2bf(acc[i][j][r]);
      }
    }
  }
}

// ---------------- V pre-transpose: QKV V-cols -> Vg[bh][d][s] ----------------
__global__ __launch_bounds__(256) void vtrans(const unsigned short* __restrict__ QKV,
                                              unsigned short* __restrict__ Vg)
{
  __shared__ unsigned T[64 * 33];   // dword matrix [d][s-pair], pad 33 (2-way free)
  const int tid = threadIdx.x;
  const int sblk = blockIdx.x, bh = blockIdx.y, b = bh >> 4, h = bh & 15;
  const unsigned short* src = QKV + (size_t)(b*2048 + sblk*64) * 3072 + 2048 + h*64;

  // load 2 s-rows x 8 d, pack s-pairs, write dwords
  {
    int sp = tid >> 3, dg = (tid & 7) * 8;      // sp in [0,32), dg in {0..56}
    short8 v0 = *(const short8*)(src + (size_t)(2*sp    ) * 3072 + dg);
    short8 v1 = *(const short8*)(src + (size_t)(2*sp + 1) * 3072 + dg);
    #pragma unroll
    for (int j = 0; j < 8; j++){
      unsigned pair = ((unsigned)(unsigned short)v0[j]) | (((unsigned)(unsigned short)v1[j]) << 16);
      T[(dg + j) * 33 + sp] = pair;
    }
  }
  __syncthreads();
  // read row d, 8 s-pairs, store 16 consecutive s
  {
    int d = tid >> 2, spg = (tid & 3) * 8;      // d in [0,64), spg in {0,8,16,24}
    unsigned tmp[8];
    #pragma unroll
    for (int j = 0; j < 8; j++) tmp[j] = T[d * 33 + spg + j];
    unsigned short* dst = Vg + ((size_t)bh*64 + d) * 2048 + sblk*64 + spg*2;
    *(short8*)(dst)     = *(short8*)&tmp[0];
    *(short8*)(dst + 8) = *(short8*)&tmp[4];
  }
}

// ---------------- attention: key-split waves, S^T trick, zero P round-trip ----
// Grid (32 qblk, 32 bh). Block 256 = 4 waves; wave w owns keys [w*16, w*16+16) of
// each 64-key chunk, all 64 q of the block as register B-fragments.
__global__ __launch_bounds__(256) void attn(const unsigned short* __restrict__ QKV,
                                            const unsigned short* __restrict__ Vg,
                                            const unsigned char* __restrict__ mask8,
                                            unsigned short* __restrict__ O)
{
  __shared__ char smem[17408];
  unsigned short* Ks = (unsigned short*)smem;            // 8 KB [key][d], xor-swizzled 16B blocks
  unsigned short* Vt = (unsigned short*)(smem + 8192);   // 8 KB [d][key], xor-swizzled
  float* lsums = (float*)(smem + 16384);                 // 1 KB [wave][q]
  float* red   = (float*)smem;                           // 16 KB, aliases Ks+Vt after loop

  const int tid = threadIdx.x, wave = tid >> 6, lane = tid & 63;
  const int l16 = lane & 15, quad = lane >> 4;
  const int bh = blockIdx.y, b = bh >> 4, h = bh & 15;
  const int qblk = blockIdx.x * 64;
  const unsigned short* Qbase = QKV + (size_t)b * 2048 * 3072 + h * 64;
  const unsigned short* Kbase = Qbase + 1024;
  const unsigned short* Vbase = Vg + (size_t)bh * 64 * 2048;
  const unsigned char*  mbase = mask8 + (size_t)b * 2048 * 2048;

  // Q B-fragments, resident in registers: B[n=q=l16][k=d=ks*32+quad*8+j]
  short8 qf[4][2];
  #pragma unroll
  for (int nt = 0; nt < 4; nt++)
    #pragma unroll
    for (int ks = 0; ks < 2; ks++)
      qf[nt][ks] = *(const short8*)(Qbase + (size_t)(qblk + nt*16 + l16) * 3072 + ks*32 + quad*8);

  f32x4 oacc[4][4] = {};            // [dtile][ntile]: O^T(d=dt*16+quad*4+r, q=nt*16+l16)
  float plsum[4] = {0.f, 0.f, 0.f, 0.f};
  const int sw = l16 & 7;           // xor swizzle key for this lane's LDS reads

  for (int j0 = 0; j0 < 2048; j0 += 64){
    __syncthreads();
    #pragma unroll
    for (int it = 0; it < 2; it++){
      int s = it * 256 + tid;
      int row = s >> 3, blk = s & 7, bg = blk ^ (row & 7);
      stage16(Kbase + (size_t)(j0 + row) * 3072 + bg * 8, Ks + s * 8);
      stage16(Vbase + (size_t)row * 2048 + j0 + bg * 8, Vt + s * 8);
    }
    __syncthreads();

    // S^T = K * Q^T : m = wave's 16 keys, n = 64 q (4 tiles), k = d = 64 (2 steps)
    short8 kf0 = *(const short8*)&Ks[(wave*16 + l16) * 64 + ((0*4 + quad) ^ sw) * 8];
    short8 kf1 = *(const short8*)&Ks[(wave*16 + l16) * 64 + ((1*4 + quad) ^ sw) * 8];
    f32x4 sacc[4];
    #pragma unroll
    for (int nt = 0; nt < 4; nt++){
      f32x4 a = {0.f, 0.f, 0.f, 0.f};
      a = __builtin_amdgcn_mfma_f32_16x16x32_bf16(kf0, qf[nt][0], a, 0, 0, 0);
      a = __builtin_amdgcn_mfma_f32_16x16x32_bf16(kf1, qf[nt][1], a, 0, 0, 0);
      sacc[nt] = a;
    }

    // mask + exp + pack directly into PV B-fragments (D-layout == B-layout for 16x16x16)
    short4v b2[4];
    const int kbyte = j0 + wave*16 + quad*4;
    #pragma unroll
    for (int nt = 0; nt < 4; nt++){
      unsigned md = *(const unsigned*)(mbase + (size_t)(qblk + nt*16 + l16) * 2048 + kbyte);
      float p0 = __expf(sacc[nt][0] * (float)( md        & 255u));
      float p1 = __expf(sacc[nt][1] * (float)((md >>  8) & 255u));
      float p2 = __expf(sacc[nt][2] * (float)((md >> 16) & 255u));
      float p3 = __expf(sacc[nt][3] * (float)( md >> 24        ));
      plsum[nt] += (p0 + p1) + (p2 + p3);
      unsigned u0 = pack_bf16_rn(p0, p1), u1 = pack_bf16_rn(p2, p3);
      union { unsigned u[2]; short4v s; } pk; pk.u[0] = u0; pk.u[1] = u1;
      b2[nt] = pk.s;
    }

    // O^T += V^T * P^T : A[m=d=l16][k=key=quad*4+j] from Vt; B = b2 (in regs)
    #pragma unroll
    for (int dt = 0; dt < 4; dt++){
      int physb = (wave*2 + (quad >> 1)) ^ sw;
      short4v a2 = *(const short4v*)&Vt[(dt*16 + l16) * 64 + physb * 8 + (quad & 1) * 4];
      #pragma unroll
      for (int nt = 0; nt < 4; nt++)
        oacc[dt][nt] = __builtin_amdgcn_mfma_f32_16x16x16bf16_1k(a2, b2[nt], oacc[dt][nt], 0, 0, 0);
    }
  }

  // ---- epilogue: wave-local lsum reduce, then serial cross-wave O reduction ----
  float lw[4];
  #pragma unroll
  for (int nt = 0; nt < 4; nt++){
    float v = plsum[nt];
    v += __shfl_xor(v, 16);
    v += __shfl_xor(v, 32);
    lw[nt] = v;
  }
  __syncthreads();                   // all chunk reads done; safe to alias red over Ks/Vt
  if (quad == 0){
    #pragma unroll
    for (int nt = 0; nt < 4; nt++) lsums[wave*64 + nt*16 + l16] = lw[nt];
  }
  if (wave == 0){
    #pragma unroll
    for (int dt = 0; dt < 4; dt++)
      #pragma unroll
      for (int nt = 0; nt < 4; nt++)
        *(f32x4*)&red[((dt*4 + nt)*64 + lane)*4] = oacc[dt][nt];
  }
  __syncthreads();
  for (int w = 1; w <= 2; w++){
    if (wave == w){
      #pragma unroll
      for (int dt = 0; dt < 4; dt++)
        #pragma unroll
        for (int nt = 0; nt < 4; nt++){
          f32x4* p = (f32x4*)&red[((dt*4 + nt)*64 + lane)*4];
          *p = *p + oacc[dt][nt];
        }
    }
    __syncthreads();
  }
  if (wave == 3){
    float linv[4];
    #pragma unroll
    for (int nt = 0; nt < 4; nt++){
      int q = nt*16 + l16;
      linv[nt] = 1.0f / (lsums[q] + lsums[64 + q] + lsums[128 + q] + lsums[192 + q]);
    }
    #pragma unroll
    for (int dt = 0; dt < 4; dt++)
      #pragma unroll
      for (int nt = 0; nt < 4; nt++){
        f32x4 t = *(f32x4*)&red[((dt*4 + nt)*64 + lane)*4];
        t = t + oacc[dt][nt];
        unsigned u0 = pack_bf16_rn(t[0] * linv[nt], t[1] * linv[nt]);
        unsigned u1 = pack_bf16_rn(t[2] * linv[nt], t[3] * linv[nt]);
        uint2 st; st.x = u0; st.y = u1;
        *(uint2*)&O[(size_t)(b*2048 + qblk + nt*16 + l16) * 1024 + h*64 + dt*16 + quad*4] = st;
      }
  }
}

// ---------------- launch ----------------
extern "C" void kernel_launch(void* const* d_in, const int* in_sizes, int n_in,
                              void* d_out, int out_size, void* d_ws, size_t ws_size,
                              hipStream_t stream)
{
  const float* X  = (const float*)d_in[0];
  const int*   Mk = (const int*)d_in[1];
  const float* Wq = (const float*)d_in[2];
  const float* Wk = (const float*)d_in[3];
  const float* Wv = (const float*)d_in[4];
  const float* Wo = (const float*)d_in[5];
  float* out = (float*)d_out;

  char* ws = (char*)d_ws;
  unsigned short* Xb   = (unsigned short*)(ws + 0);          //  8 MB  [4096][1024]
  unsigned short* Wqkv = (unsigned short*)(ws + 8388608);    //  6 MB  [3072][1024]
  unsigned short* Wob  = (unsigned short*)(ws + 14680064);   //  2 MB  [1024][1024]
  unsigned short* QKV  = (unsigned short*)(ws + 16777216);   // 24 MB  [4096][3072]
  unsigned short* Ob   = (unsigned short*)(ws + 41943040);   //  8 MB  [4096][1024]
  unsigned char*  M8   = (unsigned char*) (ws + 50331648);   //  8 MB  [2][2048][2048]
  unsigned short* Vg   = (unsigned short*)(ws + 58720256);   //  8 MB  [32][64][2048]

  cvt4<<<4096, 256, 0, stream>>>(X,  Xb,              4194304, 1.0f);
  cvt4<<<1024, 256, 0, stream>>>(Wq, Wqkv,            1048576, 0.125f); // fold 1/sqrt(64)
  cvt4<<<1024, 256, 0, stream>>>(Wk, Wqkv + 1048576,  1048576, 1.0f);
  cvt4<<<1024, 256, 0, stream>>>(Wv, Wqkv + 2097152,  1048576, 1.0f);
  cvt4<<<1024, 256, 0, stream>>>(Wo, Wob,             1048576, 1.0f);
  cvt_mask<<<8192, 256, 0, stream>>>(Mk, M8, 8388608);

  gemm_bt<false><<<dim3(32, 24), 256, 0, stream>>>(Xb, Wqkv, QKV, nullptr, 4096, 3072, 1024);
  vtrans<<<dim3(32, 32), 256, 0, stream>>>(QKV, Vg);
  attn<<<dim3(32, 32), 256, 0, stream>>>(QKV, Vg, M8, Ob);
  gemm_bt<true><<<dim3(32, 8), 256, 0, stream>>>(Ob, Wob, nullptr, out, 4096, 1024, 1024);
}